// Round 6
// baseline (649.342 us; speedup 1.0000x reference)
//
#include <hip/hip_runtime.h>
#include <hip/hip_bf16.h>

#define N_Q     100000
#define N_FEATC 192
#define N_LON   720
#define N_LAT   360
#define N_CELLS (N_LON * N_LAT)
#define HIDD    256
#define OUT_DIM 8
#define M_TILE  64
#define FSTRIDE N_CELLS
#define GRID_P  256
#define NTILES  ((N_Q + M_TILE - 1) / M_TILE)   /* 1563 */
#define MAXIT   ((NTILES + GRID_P - 1) / GRID_P) /* 7 */

/* prep-kernel grid partition */
#define TPB    1350                 /* transpose: 192 cells/block            */
#define PREB   391                  /* precompute: 256 queries/block         */
#define W1BASE (TPB + PREB)         /* 32 blocks: W1 8-row bands             */
#define W2BASE (W1BASE + 32)        /* 32 blocks: W2 8-row bands             */
#define W3BASE (W2BASE + 32)        /* 1 block:  W3                          */
#define PREP_BLOCKS (W3BASE + 1)    /* 1806                                  */

typedef float  f32x4  __attribute__((ext_vector_type(4)));
typedef __bf16 bf16x8 __attribute__((ext_vector_type(8)));
typedef __bf16 bf16x2 __attribute__((ext_vector_type(2)));

// exact-form gelu (tanh approx) — used by fp32 fixup path only
__device__ __forceinline__ float gelu_tanh(float x) {
    float u = 0.7978845608028654f * (x + 0.044715f * x * x * x);
    return 0.5f * x * (1.0f + tanhf(u));
}

// fast gelu for the bf16 hot path: 0.5x(1+tanh(u)) == x*sigmoid(2u)
//   = x * rcp(1 + exp(-2u)).  ~6 VALU ops vs ~25-40 for libm tanhf.
// Error ~3e-7 relative pre-quantization — masked by bf16 hidden rounding.
// Saturation: x<<0 -> exp=+inf -> rcp=0 -> g=0;  x>>0 -> exp=0 -> g=x.
// (round 5: -35 us measured — tanhf WAS the fused_mlp VALU floor)
#define GELU_C1 (-1.5957691216057308f)   /* -2*0.7978845608028654        */
#define GELU_C2 (-0.0713548162726143f)   /* GELU_C1 * 0.044715           */
__device__ __forceinline__ float gelu_fast(float x) {
    float t = x * x;
    float y = x * fmaf(t, GELU_C2, GELU_C1);       // y = -2u
    float e = __expf(y);
    return x * __builtin_amdgcn_rcpf(1.0f + e);
}

// numpy f32 constants: pi_f = float32(np.pi); 2*pi_f is exact in f32.
#define PI_F      3.14159274101257324219f          /* 0x40490FDB */
#define TWO_PI_F  6.28318548202514648438f          /* 0x40C90FDB */
#define DEG2RAD_F ((float)0.017453292519943295)    /* 0x3C8EFA35 */

// ===== LOCKED (round 4, absmax 0.0156): bit-exact numpy-f32 argmin. =====
// Single-mul deg2rad, fmodf+adjust remainder, first-occurrence tie-break,
// contraction OFF, +-3 window around analytic bin. DO NOT TOUCH.
__device__ __forceinline__ void nearest_lon(
    const float* __restrict__ lon_grid, float lqf, int* idx, float* dlon)
{
#pragma clang fp contract(off)
    float lonq_rad = lqf * DEG2RAD_F;
    int g = (int)floor((double)lqf * 2.0 + 0.5);
    float best = 1e30f; int bi = 0x7fffffff;
    #pragma unroll
    for (int d = -3; d <= 3; ++d) {
        int c = g + d; c %= N_LON; if (c < 0) c += N_LON;
        float lr = lon_grid[c] * DEG2RAD_F;
        float a  = (lr - lonq_rad) + PI_F;
        float m  = fmodf(a, TWO_PI_F);
        if (m < 0.0f) m += TWO_PI_F;               // np.remainder adjust (b > 0)
        float ad = fabsf(m - PI_F);
        if (ad < best || (ad == best && c < bi)) { best = ad; bi = c; }
    }
    *idx = bi;
    *dlon = lqf - lon_grid[bi];                    // UNWRAPPED, as in reference
}

__device__ __forceinline__ void nearest_lat(
    const float* __restrict__ lat_grid, float laf, int* idx, float* dlat)
{
#pragma clang fp contract(off)
    float latq_rad = laf * DEG2RAD_F;
    int gl = (int)floor(((double)laf + 90.0) * (359.0 / 180.0) + 0.5);
    float best = 1e30f; int bi = 0x7fffffff;
    #pragma unroll
    for (int d = -3; d <= 3; ++d) {
        int c = gl + d; c = min(max(c, 0), N_LAT - 1);
        float lr = lat_grid[c] * DEG2RAD_F;
        float ad = fabsf(lr - latq_rad);
        if (ad < best || (ad == best && c < bi)) { best = ad; bi = c; }
    }
    *idx = bi;
    *dlat = laf - lat_grid[bi];
}

// async global -> LDS, 16B/lane: LDS dest wave-uniform base + lane*16,
// global src per-lane (carries the pre-applied swizzle).
__device__ __forceinline__ void gload_lds16(const void* g, void* l) {
    __builtin_amdgcn_global_load_lds(
        (const __attribute__((address_space(1))) unsigned int*)g,
        (__attribute__((address_space(3))) unsigned int*)l, 16, 0, 0);
}

// raw barriers: never drain vmcnt fully in the main loop (T4 counted-vmcnt)
#define BAR_LG()  asm volatile("s_waitcnt lgkmcnt(0)\n\ts_barrier" ::: "memory")
#define BAR_VM3() asm volatile("s_waitcnt vmcnt(3) lgkmcnt(0)\n\ts_barrier" ::: "memory")
#define BAR_VM0() asm volatile("s_waitcnt vmcnt(0) lgkmcnt(0)\n\ts_barrier" ::: "memory")

// ===================== prep: transpose + precompute + weights ==============
// ws layout (bf16 elems): W1t[256][256] | W2t[256][256] | W3t[16][256] |
//   ft[259200][192]; then (bytes): gidx[N_Q] | gdl[N_Q] | gdt[N_Q]
__global__ __launch_bounds__(256) void prep(
    const float* __restrict__ features,
    const float* __restrict__ lon_q, const float* __restrict__ lat_q,
    const float* __restrict__ lon_grid, const float* __restrict__ lat_grid,
    const float* __restrict__ W1, const float* __restrict__ W2,
    const float* __restrict__ W3, __bf16* __restrict__ ws,
    __bf16* __restrict__ ft, int* __restrict__ gidx,
    float* __restrict__ gdl, float* __restrict__ gdt,
    int use_ft, int use_pre)
{
    __shared__ __attribute__((aligned(16))) char smem[76800];
    const int b = blockIdx.x;
    const int t = threadIdx.x;

    if (b < TPB) {
        // ---- features[192][259200] fp32 -> ft[259200][192] bf16 ----
        if (!use_ft) return;
        __bf16 (*lds_t)[200] = (__bf16(*)[200])smem;   // 400B rows = 25*16
        const int cb = b * 192;
        // phase 1: 96 feature-pairs x 48 cell-quads = 4608 items
        for (int g = t; g < 4608; g += 256) {
            int f2 = g / 48;
            int c4 = (g - f2 * 48) * 4;
            const float* pa = features + (size_t)(2 * f2) * N_CELLS + cb + c4;
            float4 va = *reinterpret_cast<const float4*>(pa);
            float4 vb = *reinterpret_cast<const float4*>(pa + N_CELLS);
            #pragma unroll
            for (int j = 0; j < 4; ++j) {
                bf16x2 pk;
                pk[0] = (__bf16)(&va.x)[j];
                pk[1] = (__bf16)(&vb.x)[j];
                *reinterpret_cast<bf16x2*>(&lds_t[c4 + j][2 * f2]) = pk;
            }
        }
        __syncthreads();
        // phase 2: 192 cells x 24 chunks of 16B, linear global writes
        for (int o = t; o < 4608; o += 256) {
            int cell = o / 24;
            int s    = o - cell * 24;
            int4 v = *reinterpret_cast<const int4*>(&lds_t[cell][s * 8]);
            *reinterpret_cast<int4*>(ft + (size_t)(cb + cell) * N_FEATC + s * 8) = v;
        }
    } else if (b < W1BASE) {
        // ---- per-query LOCKED argmin: gidx/gdl/gdt ----
        if (!use_pre) return;
        int q = (b - TPB) * 256 + t;
        if (q >= N_Q) return;
        int li, la; float dl, dt;
        nearest_lon(lon_grid, lon_q[q], &li, &dl);
        nearest_lat(lat_grid, lat_q[q], &la, &dt);
        gidx[q] = li * N_LAT + la;
        gdl[q] = dl; gdt[q] = dt;
    } else if (b < W3BASE) {
        // ---- W1/W2 -> bf16 transposed, 8-row bands, coalesced reads ----
        if (!use_ft) return;
        float (*sub)[256] = (float(*)[256])smem;
        const int  isW2 = (b >= W2BASE);
        const int  band = b - (isW2 ? W2BASE : W1BASE);
        const float* Ws = isW2 ? W2 : W1;
        const int  kmax = isW2 ? 256 : 194;
        __bf16*    dst  = ws + (isW2 ? 65536 : 0);
        const int  k0   = band * 8;
        #pragma unroll
        for (int j = 0; j < 8; ++j) {
            int k = k0 + j;
            sub[j][t] = (k < kmax) ? Ws[k * 256 + t] : 0.0f;
        }
        __syncthreads();
        bf16x8 o;
        #pragma unroll
        for (int j = 0; j < 8; ++j) o[j] = (__bf16)sub[j][t];
        *reinterpret_cast<bf16x8*>(dst + (size_t)t * 256 + k0) = o;   // ws[n][k0..k0+7]
    } else {
        if (!use_ft) return;
        for (int idx = t; idx < 4096; idx += 256) {
            int n = idx >> 8, k = idx & 255;
            float v = (n < 8) ? W3[k * 8 + n] : 0.0f;
            ws[131072 + idx] = (__bf16)v;
        }
    }
}

// ======= fp32 exact row, 512-thread variant (barriers uniform, t<256 compute)
__device__ __forceinline__ void mlp_row_fp32_512(
    int q, int gb, float dl, float dt, int t,
    const float* __restrict__ features,
    const float* __restrict__ W1f, const float* __restrict__ b1f,
    const float* __restrict__ W2f, const float* __restrict__ b2f,
    const float* __restrict__ W3f, const float* __restrict__ b3f,
    float* __restrict__ out, float* xs, float* h1s, float* h2s)
{
    if (t < 194)
        xs[t] = (t < 192) ? features[(size_t)t * FSTRIDE + gb]
                          : (t == 192 ? dl : dt);
    __syncthreads();
    if (t < 256) {   // layer 1: col = t, 16-way batched loads
        float acc = b1f[t];
        int k = 0;
        for (; k + 16 <= 194; k += 16) {
            float w[16];
            #pragma unroll
            for (int u = 0; u < 16; ++u) w[u] = W1f[(k + u) * 256 + t];
            #pragma unroll
            for (int u = 0; u < 16; ++u) acc = fmaf(xs[k + u], w[u], acc);
        }
        for (; k < 194; ++k) acc = fmaf(xs[k], W1f[k * 256 + t], acc);
        h1s[t] = gelu_tanh(acc);
    }
    __syncthreads();
    if (t < 256) {   // layer 2
        float acc = b2f[t];
        for (int k = 0; k < 256; k += 16) {
            float w[16];
            #pragma unroll
            for (int u = 0; u < 16; ++u) w[u] = W2f[(k + u) * 256 + t];
            #pragma unroll
            for (int u = 0; u < 16; ++u) acc = fmaf(h1s[k + u], w[u], acc);
        }
        h2s[t] = gelu_tanh(acc);
    }
    __syncthreads();
    if (t < 64) {    // layer 3: 8 lanes/output x 8 outputs, shfl-reduce (wave 0)
        int j = t & 7, ch = t >> 3;
        float a3 = 0.0f;
        for (int k = ch * 32; k < ch * 32 + 32; ++k)
            a3 = fmaf(h2s[k], W3f[k * 8 + j], a3);
        #pragma unroll
        for (int off = 8; off < 64; off <<= 1) a3 += __shfl_down(a3, off);
        if (t < 8) out[q * 8 + t] = a3 + b3f[t];
    }
    __syncthreads();
}

// ===================== persistent fused MLP (hot path) =====================
// 512 threads = 8 waves, 1 block/CU (LDS-bound), grid 256. Each wave owns a
// 32-col slice of layers 1&2 with W in REGISTERS (144 VGPR, loaded once).
// 3 barriers/tile; counted vmcnt(3) keeps next tile's gathers in flight.
// Round 6: fixup_scan folded into the kernel TAIL. Each block recomputes the
// fp32 path for wrap queries (|dlon|>1) of ITS OWN tiles only — intra-block
// program order makes the fp32 overwrite safely follow the bf16 store of the
// same query (a global scan would race across blocks). List sized 448 =
// max queries/block: no overflow cliff. fp32 scratch overlays hA.
__global__ __launch_bounds__(512, 1) void fused_mlp(
    const __bf16* __restrict__ ws, const __bf16* __restrict__ ft,
    const int* __restrict__ gidx, const float* __restrict__ gdl,
    const float* __restrict__ gdt,
    const float* __restrict__ features,
    const float* __restrict__ W1, const float* __restrict__ b1,
    const float* __restrict__ W2, const float* __restrict__ b2,
    const float* __restrict__ W3, const float* __restrict__ b3,
    float* __restrict__ out)
{
    __shared__ __attribute__((aligned(16))) __bf16 gbuf[2][64 * 192]; // 2x24576B
    __shared__ __attribute__((aligned(16))) __bf16 hA[64][264];       // 33792B
    __shared__ __attribute__((aligned(16))) __bf16 hB[64][264];       // 33792B
    __shared__ float dl_s[2][64], dt_s[2][64];
    __shared__ int   fcnt;
    __shared__ int   flst[MAXIT * M_TILE];                            // 448 ints

    const int t    = threadIdx.x;
    const int lane = t & 63;
    const int wave = t >> 6;          // 0..7
    const int l15  = lane & 15;
    const int lhi  = lane >> 4;       // 0..3
    const int cw   = wave * 32;       // 32-col slice per wave

    // ---- W fragments in registers (once per block) ----
    bf16x8 w1r[2][6], w2r[2][8], w3r[8];
    #pragma unroll
    for (int nn = 0; nn < 2; ++nn) {
        const __bf16* base1 = ws + (size_t)(cw + nn * 16 + l15) * 256 + lhi * 8;
        #pragma unroll
        for (int kc = 0; kc < 6; ++kc)
            w1r[nn][kc] = *reinterpret_cast<const bf16x8*>(base1 + kc * 32);
        const __bf16* base2 = ws + 65536 + (size_t)(cw + nn * 16 + l15) * 256 + lhi * 8;
        #pragma unroll
        for (int kc = 0; kc < 8; ++kc)
            w2r[nn][kc] = *reinterpret_cast<const bf16x8*>(base2 + kc * 32);
    }
    {
        const __bf16* base3 = ws + 131072 + (size_t)l15 * 256 + lhi * 8;
        #pragma unroll
        for (int kc = 0; kc < 8; ++kc)
            w3r[kc] = *reinterpret_cast<const bf16x8*>(base3 + kc * 32);
    }
    float w1d0[2], w1d1[2], bb1[2], bb2[2];
    #pragma unroll
    for (int nn = 0; nn < 2; ++nn) {
        int col = cw + nn * 16 + l15;
        w1d0[nn] = W1[192 * 256 + col];
        w1d1[nn] = W1[193 * 256 + col];
        bb1[nn]  = b1[col];
        bb2[nn]  = b2[col];
    }
    const float bb3 = b3[l15 < OUT_DIM ? l15 : 0];

    if (t == 0) fcnt = 0;   // covered by first barrier inside the loop

    // prefetch tile T2 into buffer nb: dl/dt staging + swizzled gathers
    auto phaseB = [&](int T2, int nb) {
        float stage_v = 0.0f;
        if (t < 128) {
            int g = t & 63;
            int q = T2 * M_TILE + g; if (q >= N_Q) q = N_Q - 1;
            stage_v = (t < 64) ? gdl[q] : gdt[q];
        }
        {
            // hoist all 3 gidx loads ahead of the DMA issues (single vm-wait)
            int gbv[3], sofv[3], rowv[3];
            #pragma unroll
            for (int j = 0; j < 3; ++j) {
                int u   = (wave * 3 + j) * 64 + lane;     // 16B-chunk 0..1535
                int row = u / 24;                          // query row 0..63
                rowv[j] = row;
                sofv[j] = (u - row * 24) * 16;             // byte in row
                int q = T2 * M_TILE + row; if (q >= N_Q) q = N_Q - 1;
                gbv[j] = gidx[q];
            }
            char* dstbase = (char*)&gbuf[nb][0] + wave * 3 * 1024;
            #pragma unroll
            for (int j = 0; j < 3; ++j) {
                const char* src = (const char*)ft + (size_t)gbv[j] * 384
                                  + (sofv[j] ^ ((rowv[j] & 7) << 4));
                gload_lds16(src, dstbase + j * 1024);
            }
        }
        if (t < 128) {
            int g = t & 63;
            if (t < 64) dl_s[nb][g] = stage_v; else dt_s[nb][g] = stage_v;
        }
    };

    const int Tb    = (int)blockIdx.x;
    const int nIter = (NTILES - Tb + GRID_P - 1) / GRID_P;   // 6 or 7

    phaseB(Tb, 0);                    // prologue: stage tile 0

    int cur = 0;
    for (int i = 0; i < nIter; ++i) {
        const int T = Tb + i * GRID_P;
        const bool hasNext = (i + 1 < nIter);
        if (hasNext) phaseB(Tb + (i + 1) * GRID_P, cur ^ 1);
        if (hasNext) { BAR_VM3(); } else { BAR_VM0(); }

        const char* gby = (const char*)&gbuf[cur][0];
        const int   swz = (lane & 7) << 4;

        // ---- layer 1: K=192 from gbuf (pad chunks were exact zeros) ----
        #pragma unroll
        for (int m = 0; m < 4; ++m) {
            f32x4 acc0 = {0.f, 0.f, 0.f, 0.f}, acc1 = {0.f, 0.f, 0.f, 0.f};
            __builtin_amdgcn_s_setprio(1);
            #pragma unroll
            for (int kc = 0; kc < 6; ++kc) {
                const bf16x8 a = *reinterpret_cast<const bf16x8*>(
                    gby + (m * 16 + l15) * 384 + ((kc * 64 + lhi * 16) ^ swz));
                acc0 = __builtin_amdgcn_mfma_f32_16x16x32_bf16(a, w1r[0][kc], acc0, 0, 0, 0);
                acc1 = __builtin_amdgcn_mfma_f32_16x16x32_bf16(a, w1r[1][kc], acc1, 0, 0, 0);
            }
            __builtin_amdgcn_s_setprio(0);
            float dlv[4], dtv[4];
            #pragma unroll
            for (int r = 0; r < 4; ++r) {
                int row = m * 16 + lhi * 4 + r;
                dlv[r] = dl_s[cur][row]; dtv[r] = dt_s[cur][row];
            }
            #pragma unroll
            for (int r = 0; r < 4; ++r) {
                int row = m * 16 + lhi * 4 + r;
                float v0 = acc0[r] + dlv[r] * w1d0[0] + dtv[r] * w1d1[0] + bb1[0];
                float v1 = acc1[r] + dlv[r] * w1d0[1] + dtv[r] * w1d1[1] + bb1[1];
                hA[row][cw + l15]      = (__bf16)gelu_fast(v0);
                hA[row][cw + 16 + l15] = (__bf16)gelu_fast(v1);
            }
        }
        BAR_LG();

        // ---- layer 2: K=256 from hA ----
        #pragma unroll
        for (int m = 0; m < 4; ++m) {
            f32x4 acc0 = {0.f, 0.f, 0.f, 0.f}, acc1 = {0.f, 0.f, 0.f, 0.f};
            __builtin_amdgcn_s_setprio(1);
            #pragma unroll
            for (int kc = 0; kc < 8; ++kc) {
                const bf16x8 a = *reinterpret_cast<const bf16x8*>(
                    &hA[m * 16 + l15][kc * 32 + lhi * 8]);
                acc0 = __builtin_amdgcn_mfma_f32_16x16x32_bf16(a, w2r[0][kc], acc0, 0, 0, 0);
                acc1 = __builtin_amdgcn_mfma_f32_16x16x32_bf16(a, w2r[1][kc], acc1, 0, 0, 0);
            }
            __builtin_amdgcn_s_setprio(0);
            #pragma unroll
            for (int r = 0; r < 4; ++r) {
                int row = m * 16 + lhi * 4 + r;
                hB[row][cw + l15]      = (__bf16)gelu_fast(acc0[r] + bb2[0]);
                hB[row][cw + 16 + l15] = (__bf16)gelu_fast(acc1[r] + bb2[1]);
            }
        }
        BAR_LG();

        // ---- layer 3: waves 0..3, 16 rows each ----
        if (wave < 4) {
            f32x4 a3 = {0.f, 0.f, 0.f, 0.f};
            __builtin_amdgcn_s_setprio(1);
            #pragma unroll
            for (int kc = 0; kc < 8; ++kc) {
                const bf16x8 a = *reinterpret_cast<const bf16x8*>(
                    &hB[wave * 16 + l15][kc * 32 + lhi * 8]);
                a3 = __builtin_amdgcn_mfma_f32_16x16x32_bf16(a, w3r[kc], a3, 0, 0, 0);
            }
            __builtin_amdgcn_s_setprio(0);
            if (l15 < OUT_DIM) {
                #pragma unroll
                for (int r = 0; r < 4; ++r) {
                    int row = T * M_TILE + wave * 16 + lhi * 4 + r;
                    if (row < N_Q) out[row * OUT_DIM + l15] = a3[r] + bb3;
                }
            }
        }
        cur ^= 1;
    }

    // ---- tail: fp32 fixup for THIS block's own tiles (ordering-safe) ----
    __syncthreads();                       // main-loop LDS/out writes done
    for (int i = 0; i < nIter; ++i) {
        if (t < M_TILE) {
            int q = (Tb + i * GRID_P) * M_TILE + t;
            if (q < N_Q && fabsf(gdl[q]) > 1.0f) {
                int s = atomicAdd(&fcnt, 1);   // LDS atomic, block-local
                flst[s] = q;                   // s < nIter*64 by construction
            }
        }
    }
    __syncthreads();
    const int nfix = fcnt;
    if (nfix > 0) {
        float* xs  = (float*)&hA[0][0];    // overlay scratch on hA (706 floats)
        float* h1s = xs + 256;
        float* h2s = xs + 512;
        for (int e = 0; e < nfix; ++e) {
            const int q = flst[e];
            mlp_row_fp32_512(q, gidx[q], gdl[q], gdt[q], t,
                             features, W1, b1, W2, b2, W3, b3, out,
                             xs, h1s, h2s);
        }
    }
}

// =============== fp32 exact path (256-thread), fallback only ===============
__device__ __forceinline__ void mlp_row_fp32(
    int q, int gb, float dl, float dt, int t,
    const float* __restrict__ features,
    const float* __restrict__ W1, const float* __restrict__ b1,
    const float* __restrict__ W2, const float* __restrict__ b2,
    const float* __restrict__ W3, const float* __restrict__ b3,
    float* __restrict__ out, float* xs, float* h1s, float* h2s)
{
    if (t < 194)
        xs[t] = (t < 192) ? features[(size_t)t * FSTRIDE + gb]
                          : (t == 192 ? dl : dt);
    __syncthreads();
    {   // layer 1: col = t, 16-way batched loads
        float acc = b1[t];
        int k = 0;
        for (; k + 16 <= 194; k += 16) {
            float w[16];
            #pragma unroll
            for (int u = 0; u < 16; ++u) w[u] = W1[(k + u) * 256 + t];
            #pragma unroll
            for (int u = 0; u < 16; ++u) acc = fmaf(xs[k + u], w[u], acc);
        }
        for (; k < 194; ++k) acc = fmaf(xs[k], W1[k * 256 + t], acc);
        h1s[t] = gelu_tanh(acc);
    }
    __syncthreads();
    {   // layer 2
        float acc = b2[t];
        for (int k = 0; k < 256; k += 16) {
            float w[16];
            #pragma unroll
            for (int u = 0; u < 16; ++u) w[u] = W2[(k + u) * 256 + t];
            #pragma unroll
            for (int u = 0; u < 16; ++u) acc = fmaf(h1s[k + u], w[u], acc);
        }
        h2s[t] = gelu_tanh(acc);
    }
    __syncthreads();
    if (t < 64) {   // layer 3: 8 lanes/output x 8 outputs, shfl-reduce
        int j = t & 7, ch = t >> 3;
        float a3 = 0.0f;
        for (int k = ch * 32; k < ch * 32 + 32; ++k)
            a3 = fmaf(h2s[k], W3[k * 8 + j], a3);
        #pragma unroll
        for (int off = 8; off < 64; off <<= 1) a3 += __shfl_down(a3, off);
        if (t < 8) out[q * 8 + t] = a3 + b3[t];
    }
    __syncthreads();
}

// Fallback full-fp32 path (only if workspace too small — never in practice).
__global__ __launch_bounds__(256) void mlp_slow(
    const float* __restrict__ features, const float* __restrict__ lon_q,
    const float* __restrict__ lat_q, const float* __restrict__ lon_grid,
    const float* __restrict__ lat_grid,
    const float* __restrict__ W1, const float* __restrict__ b1,
    const float* __restrict__ W2, const float* __restrict__ b2,
    const float* __restrict__ W3, const float* __restrict__ b3,
    float* __restrict__ out)
{
    const int q = blockIdx.x;
    if (q >= N_Q) return;
    const int t = threadIdx.x;
    __shared__ float xs[194];
    __shared__ float h1s[HIDD];
    __shared__ float h2s[HIDD];
    int li, la; float dl, dt;
    nearest_lon(lon_grid, lon_q[q], &li, &dl);
    nearest_lat(lat_grid, lat_q[q], &la, &dt);
    mlp_row_fp32(q, li * N_LAT + la, dl, dt, t,
                 features, W1, b1, W2, b2, W3, b3, out, xs, h1s, h2s);
}

extern "C" void kernel_launch(void* const* d_in, const int* in_sizes, int n_in,
                              void* d_out, int out_size, void* d_ws, size_t ws_size,
                              hipStream_t stream)
{
    const float* features = (const float*)d_in[0];
    const float* lon_q    = (const float*)d_in[1];
    const float* lat_q    = (const float*)d_in[2];
    const float* lon_grid = (const float*)d_in[3];
    const float* lat_grid = (const float*)d_in[4];
    const float* W1       = (const float*)d_in[5];
    const float* b1       = (const float*)d_in[6];
    const float* W2       = (const float*)d_in[7];
    const float* b2       = (const float*)d_in[8];
    const float* W3       = (const float*)d_in[9];
    const float* b3       = (const float*)d_in[10];
    __bf16* ws = (__bf16*)d_ws;
    float* out = (float*)d_out;

    const size_t W_BYTES   = 135168ull * 2;                       // 270336
    const size_t FT_BYTES  = (size_t)N_CELLS * N_FEATC * 2;       // 99,532,800
    const size_t IDX_OFF   = W_BYTES + FT_BYTES;                  // 99,803,136
    const size_t PRE_BYTES = (size_t)N_Q * 12 + 64;
    const int use_ft  = (ws_size >= IDX_OFF) ? 1 : 0;
    const int use_pre = (ws_size >= IDX_OFF + PRE_BYTES) ? 1 : 0;

    __bf16* ft   = ws + 135168;
    char*  base  = (char*)d_ws;
    int*   gidx  = (int*)(base + IDX_OFF);
    float* gdl   = (float*)(base + IDX_OFF + (size_t)N_Q * 4);
    float* gdt   = (float*)(base + IDX_OFF + (size_t)N_Q * 8);

    prep<<<PREP_BLOCKS, 256, 0, stream>>>(
        features, lon_q, lat_q, lon_grid, lat_grid, W1, W2, W3,
        ws, ft, gidx, gdl, gdt, use_ft, use_pre);

    if (use_ft && use_pre) {
        fused_mlp<<<GRID_P, 512, 0, stream>>>(
            ws, ft, gidx, gdl, gdt, features,
            W1, b1, W2, b2, W3, b3, out);
    } else {
        mlp_slow<<<N_Q, 256, 0, stream>>>(
            features, lon_q, lat_q, lon_grid, lat_grid,
            W1, b1, W2, b2, W3, b3, out);
    }
}

// Round 7
// 382.168 us; speedup vs baseline: 1.6991x; 1.6991x over previous
//
#include <hip/hip_runtime.h>
#include <hip/hip_bf16.h>

#define N_Q     100000
#define N_FEATC 192
#define N_LON   720
#define N_LAT   360
#define N_CELLS (N_LON * N_LAT)
#define HIDD    256
#define OUT_DIM 8
#define M_TILE  64
#define FSTRIDE N_CELLS
#define GRID_P  256
#define NTILES  ((N_Q + M_TILE - 1) / M_TILE)   /* 1563 */

/* prep-kernel grid partition */
#define TPB    1350                 /* transpose: 192 cells/block            */
#define PREB   391                  /* precompute: 256 queries/block         */
#define W1BASE (TPB + PREB)         /* 32 blocks: W1 8-row bands             */
#define W2BASE (W1BASE + 32)        /* 32 blocks: W2 8-row bands             */
#define W3BASE (W2BASE + 32)        /* 1 block:  W3                          */
#define PREP_BLOCKS (W3BASE + 1)    /* 1806                                  */

typedef float  f32x4  __attribute__((ext_vector_type(4)));
typedef __bf16 bf16x8 __attribute__((ext_vector_type(8)));
typedef __bf16 bf16x2 __attribute__((ext_vector_type(2)));

// exact-form gelu (tanh approx) — used by fp32 fixup path only.
// ROUND-6 LESSON (DO NOT RE-FUSE): inlining this fp32/tanhf path into
// fused_mlp's tail dropped VGPR_Count to 128 (< the 144 VGPRs the weight
// fragments need) -> weights spilled to scratch -> WRITE_SIZE 3->84 MB,
// fused_mlp 30 -> 360 us. Keep the fp32 path in SEPARATE kernels only.
__device__ __forceinline__ float gelu_tanh(float x) {
    float u = 0.7978845608028654f * (x + 0.044715f * x * x * x);
    return 0.5f * x * (1.0f + tanhf(u));
}

// fast gelu for the bf16 hot path: 0.5x(1+tanh(u)) == x*sigmoid(2u)
//   = x * rcp(1 + exp(-2u)).  ~6 VALU ops vs ~25-40 for libm tanhf.
// Error ~3e-7 relative pre-quantization — masked by bf16 hidden rounding.
// Saturation: x<<0 -> exp=+inf -> rcp=0 -> g=0;  x>>0 -> exp=0 -> g=x.
// (round 5: -35 us measured — tanhf WAS the fused_mlp VALU floor)
#define GELU_C1 (-1.5957691216057308f)   /* -2*0.7978845608028654        */
#define GELU_C2 (-0.0713548162726143f)   /* GELU_C1 * 0.044715           */
__device__ __forceinline__ float gelu_fast(float x) {
    float t = x * x;
    float y = x * fmaf(t, GELU_C2, GELU_C1);       // y = -2u
    float e = __expf(y);
    return x * __builtin_amdgcn_rcpf(1.0f + e);
}

// numpy f32 constants: pi_f = float32(np.pi); 2*pi_f is exact in f32.
#define PI_F      3.14159274101257324219f          /* 0x40490FDB */
#define TWO_PI_F  6.28318548202514648438f          /* 0x40C90FDB */
#define DEG2RAD_F ((float)0.017453292519943295)    /* 0x3C8EFA35 */

// ===== LOCKED (round 4, absmax 0.0156): bit-exact numpy-f32 argmin. =====
// Single-mul deg2rad, fmodf+adjust remainder, first-occurrence tie-break,
// contraction OFF, +-3 window around analytic bin. DO NOT TOUCH.
__device__ __forceinline__ void nearest_lon(
    const float* __restrict__ lon_grid, float lqf, int* idx, float* dlon)
{
#pragma clang fp contract(off)
    float lonq_rad = lqf * DEG2RAD_F;
    int g = (int)floor((double)lqf * 2.0 + 0.5);
    float best = 1e30f; int bi = 0x7fffffff;
    #pragma unroll
    for (int d = -3; d <= 3; ++d) {
        int c = g + d; c %= N_LON; if (c < 0) c += N_LON;
        float lr = lon_grid[c] * DEG2RAD_F;
        float a  = (lr - lonq_rad) + PI_F;
        float m  = fmodf(a, TWO_PI_F);
        if (m < 0.0f) m += TWO_PI_F;               // np.remainder adjust (b > 0)
        float ad = fabsf(m - PI_F);
        if (ad < best || (ad == best && c < bi)) { best = ad; bi = c; }
    }
    *idx = bi;
    *dlon = lqf - lon_grid[bi];                    // UNWRAPPED, as in reference
}

__device__ __forceinline__ void nearest_lat(
    const float* __restrict__ lat_grid, float laf, int* idx, float* dlat)
{
#pragma clang fp contract(off)
    float latq_rad = laf * DEG2RAD_F;
    int gl = (int)floor(((double)laf + 90.0) * (359.0 / 180.0) + 0.5);
    float best = 1e30f; int bi = 0x7fffffff;
    #pragma unroll
    for (int d = -3; d <= 3; ++d) {
        int c = gl + d; c = min(max(c, 0), N_LAT - 1);
        float lr = lat_grid[c] * DEG2RAD_F;
        float ad = fabsf(lr - latq_rad);
        if (ad < best || (ad == best && c < bi)) { best = ad; bi = c; }
    }
    *idx = bi;
    *dlat = laf - lat_grid[bi];
}

// async global -> LDS, 16B/lane: LDS dest wave-uniform base + lane*16,
// global src per-lane (carries the pre-applied swizzle).
__device__ __forceinline__ void gload_lds16(const void* g, void* l) {
    __builtin_amdgcn_global_load_lds(
        (const __attribute__((address_space(1))) unsigned int*)g,
        (__attribute__((address_space(3))) unsigned int*)l, 16, 0, 0);
}

// raw barriers: never drain vmcnt fully in the main loop (T4 counted-vmcnt)
#define BAR_LG()  asm volatile("s_waitcnt lgkmcnt(0)\n\ts_barrier" ::: "memory")
#define BAR_VM3() asm volatile("s_waitcnt vmcnt(3) lgkmcnt(0)\n\ts_barrier" ::: "memory")
#define BAR_VM0() asm volatile("s_waitcnt vmcnt(0) lgkmcnt(0)\n\ts_barrier" ::: "memory")

// ===================== prep: transpose + precompute + weights ==============
// ws layout (bf16 elems): W1t[256][256] | W2t[256][256] | W3t[16][256] |
//   ft[259200][192]; then (bytes): gidx[N_Q] | gdl[N_Q] | gdt[N_Q]
__global__ __launch_bounds__(256) void prep(
    const float* __restrict__ features,
    const float* __restrict__ lon_q, const float* __restrict__ lat_q,
    const float* __restrict__ lon_grid, const float* __restrict__ lat_grid,
    const float* __restrict__ W1, const float* __restrict__ W2,
    const float* __restrict__ W3, __bf16* __restrict__ ws,
    __bf16* __restrict__ ft, int* __restrict__ gidx,
    float* __restrict__ gdl, float* __restrict__ gdt,
    int use_ft, int use_pre)
{
    __shared__ __attribute__((aligned(16))) char smem[76800];
    const int b = blockIdx.x;
    const int t = threadIdx.x;

    if (b < TPB) {
        // ---- features[192][259200] fp32 -> ft[259200][192] bf16 ----
        if (!use_ft) return;
        __bf16 (*lds_t)[200] = (__bf16(*)[200])smem;   // 400B rows = 25*16
        const int cb = b * 192;
        // phase 1: 96 feature-pairs x 48 cell-quads = 4608 items
        for (int g = t; g < 4608; g += 256) {
            int f2 = g / 48;
            int c4 = (g - f2 * 48) * 4;
            const float* pa = features + (size_t)(2 * f2) * N_CELLS + cb + c4;
            float4 va = *reinterpret_cast<const float4*>(pa);
            float4 vb = *reinterpret_cast<const float4*>(pa + N_CELLS);
            #pragma unroll
            for (int j = 0; j < 4; ++j) {
                bf16x2 pk;
                pk[0] = (__bf16)(&va.x)[j];
                pk[1] = (__bf16)(&vb.x)[j];
                *reinterpret_cast<bf16x2*>(&lds_t[c4 + j][2 * f2]) = pk;
            }
        }
        __syncthreads();
        // phase 2: 192 cells x 24 chunks of 16B, linear global writes
        for (int o = t; o < 4608; o += 256) {
            int cell = o / 24;
            int s    = o - cell * 24;
            int4 v = *reinterpret_cast<const int4*>(&lds_t[cell][s * 8]);
            *reinterpret_cast<int4*>(ft + (size_t)(cb + cell) * N_FEATC + s * 8) = v;
        }
    } else if (b < W1BASE) {
        // ---- per-query LOCKED argmin: gidx/gdl/gdt ----
        if (!use_pre) return;
        int q = (b - TPB) * 256 + t;
        if (q >= N_Q) return;
        int li, la; float dl, dt;
        nearest_lon(lon_grid, lon_q[q], &li, &dl);
        nearest_lat(lat_grid, lat_q[q], &la, &dt);
        gidx[q] = li * N_LAT + la;
        gdl[q] = dl; gdt[q] = dt;
    } else if (b < W3BASE) {
        // ---- W1/W2 -> bf16 transposed, 8-row bands, coalesced reads ----
        if (!use_ft) return;
        float (*sub)[256] = (float(*)[256])smem;
        const int  isW2 = (b >= W2BASE);
        const int  band = b - (isW2 ? W2BASE : W1BASE);
        const float* Ws = isW2 ? W2 : W1;
        const int  kmax = isW2 ? 256 : 194;
        __bf16*    dst  = ws + (isW2 ? 65536 : 0);
        const int  k0   = band * 8;
        #pragma unroll
        for (int j = 0; j < 8; ++j) {
            int k = k0 + j;
            sub[j][t] = (k < kmax) ? Ws[k * 256 + t] : 0.0f;
        }
        __syncthreads();
        bf16x8 o;
        #pragma unroll
        for (int j = 0; j < 8; ++j) o[j] = (__bf16)sub[j][t];
        *reinterpret_cast<bf16x8*>(dst + (size_t)t * 256 + k0) = o;   // ws[n][k0..k0+7]
    } else {
        if (!use_ft) return;
        for (int idx = t; idx < 4096; idx += 256) {
            int n = idx >> 8, k = idx & 255;
            float v = (n < 8) ? W3[k * 8 + n] : 0.0f;
            ws[131072 + idx] = (__bf16)v;
        }
    }
}

// ===================== persistent fused MLP (hot path) =====================
// 512 threads = 8 waves, 1 block/CU (LDS-bound), grid 256. Each wave owns a
// 32-col slice of layers 1&2 with W in REGISTERS (144 VGPR, loaded once).
// 3 barriers/tile; counted vmcnt(3) keeps next tile's gathers in flight.
// NO fp32/tanhf code in this kernel (round-6 spill lesson, see gelu_tanh).
__global__ __launch_bounds__(512, 1) void fused_mlp(
    const __bf16* __restrict__ ws, const __bf16* __restrict__ ft,
    const int* __restrict__ gidx, const float* __restrict__ gdl,
    const float* __restrict__ gdt, const float* __restrict__ W1,
    const float* __restrict__ b1, const float* __restrict__ b2,
    const float* __restrict__ b3, float* __restrict__ out)
{
    __shared__ __attribute__((aligned(16))) __bf16 gbuf[2][64 * 192]; // 2x24576B
    __shared__ __attribute__((aligned(16))) __bf16 hA[64][264];       // 33792B
    __shared__ __attribute__((aligned(16))) __bf16 hB[64][264];       // 33792B
    __shared__ float dl_s[2][64], dt_s[2][64];

    const int t    = threadIdx.x;
    const int lane = t & 63;
    const int wave = t >> 6;          // 0..7
    const int l15  = lane & 15;
    const int lhi  = lane >> 4;       // 0..3
    const int cw   = wave * 32;       // 32-col slice per wave

    // ---- W fragments in registers (once per block) ----
    bf16x8 w1r[2][6], w2r[2][8], w3r[8];
    #pragma unroll
    for (int nn = 0; nn < 2; ++nn) {
        const __bf16* base1 = ws + (size_t)(cw + nn * 16 + l15) * 256 + lhi * 8;
        #pragma unroll
        for (int kc = 0; kc < 6; ++kc)
            w1r[nn][kc] = *reinterpret_cast<const bf16x8*>(base1 + kc * 32);
        const __bf16* base2 = ws + 65536 + (size_t)(cw + nn * 16 + l15) * 256 + lhi * 8;
        #pragma unroll
        for (int kc = 0; kc < 8; ++kc)
            w2r[nn][kc] = *reinterpret_cast<const bf16x8*>(base2 + kc * 32);
    }
    {
        const __bf16* base3 = ws + 131072 + (size_t)l15 * 256 + lhi * 8;
        #pragma unroll
        for (int kc = 0; kc < 8; ++kc)
            w3r[kc] = *reinterpret_cast<const bf16x8*>(base3 + kc * 32);
    }
    float w1d0[2], w1d1[2], bb1[2], bb2[2];
    #pragma unroll
    for (int nn = 0; nn < 2; ++nn) {
        int col = cw + nn * 16 + l15;
        w1d0[nn] = W1[192 * 256 + col];
        w1d1[nn] = W1[193 * 256 + col];
        bb1[nn]  = b1[col];
        bb2[nn]  = b2[col];
    }
    const float bb3 = b3[l15 < OUT_DIM ? l15 : 0];

    // prefetch tile T2 into buffer nb: dl/dt staging + swizzled gathers
    auto phaseB = [&](int T2, int nb) {
        float stage_v = 0.0f;
        if (t < 128) {
            int g = t & 63;
            int q = T2 * M_TILE + g; if (q >= N_Q) q = N_Q - 1;
            stage_v = (t < 64) ? gdl[q] : gdt[q];
        }
        {
            // hoist all 3 gidx loads ahead of the DMA issues (single vm-wait)
            int gbv[3], sofv[3], rowv[3];
            #pragma unroll
            for (int j = 0; j < 3; ++j) {
                int u   = (wave * 3 + j) * 64 + lane;     // 16B-chunk 0..1535
                int row = u / 24;                          // query row 0..63
                rowv[j] = row;
                sofv[j] = (u - row * 24) * 16;             // byte in row
                int q = T2 * M_TILE + row; if (q >= N_Q) q = N_Q - 1;
                gbv[j] = gidx[q];
            }
            char* dstbase = (char*)&gbuf[nb][0] + wave * 3 * 1024;
            #pragma unroll
            for (int j = 0; j < 3; ++j) {
                const char* src = (const char*)ft + (size_t)gbv[j] * 384
                                  + (sofv[j] ^ ((rowv[j] & 7) << 4));
                gload_lds16(src, dstbase + j * 1024);
            }
        }
        if (t < 128) {
            int g = t & 63;
            if (t < 64) dl_s[nb][g] = stage_v; else dt_s[nb][g] = stage_v;
        }
    };

    const int Tb    = (int)blockIdx.x;
    const int nIter = (NTILES - Tb + GRID_P - 1) / GRID_P;   // 6 or 7

    phaseB(Tb, 0);                    // prologue: stage tile 0

    int cur = 0;
    for (int i = 0; i < nIter; ++i) {
        const int T = Tb + i * GRID_P;
        const bool hasNext = (i + 1 < nIter);
        if (hasNext) phaseB(Tb + (i + 1) * GRID_P, cur ^ 1);
        if (hasNext) { BAR_VM3(); } else { BAR_VM0(); }

        const char* gby = (const char*)&gbuf[cur][0];
        const int   swz = (lane & 7) << 4;

        // ---- layer 1: K=192 from gbuf (pad chunks were exact zeros) ----
        #pragma unroll
        for (int m = 0; m < 4; ++m) {
            f32x4 acc0 = {0.f, 0.f, 0.f, 0.f}, acc1 = {0.f, 0.f, 0.f, 0.f};
            __builtin_amdgcn_s_setprio(1);
            #pragma unroll
            for (int kc = 0; kc < 6; ++kc) {
                const bf16x8 a = *reinterpret_cast<const bf16x8*>(
                    gby + (m * 16 + l15) * 384 + ((kc * 64 + lhi * 16) ^ swz));
                acc0 = __builtin_amdgcn_mfma_f32_16x16x32_bf16(a, w1r[0][kc], acc0, 0, 0, 0);
                acc1 = __builtin_amdgcn_mfma_f32_16x16x32_bf16(a, w1r[1][kc], acc1, 0, 0, 0);
            }
            __builtin_amdgcn_s_setprio(0);
            float dlv[4], dtv[4];
            #pragma unroll
            for (int r = 0; r < 4; ++r) {
                int row = m * 16 + lhi * 4 + r;
                dlv[r] = dl_s[cur][row]; dtv[r] = dt_s[cur][row];
            }
            #pragma unroll
            for (int r = 0; r < 4; ++r) {
                int row = m * 16 + lhi * 4 + r;
                float v0 = acc0[r] + dlv[r] * w1d0[0] + dtv[r] * w1d1[0] + bb1[0];
                float v1 = acc1[r] + dlv[r] * w1d0[1] + dtv[r] * w1d1[1] + bb1[1];
                hA[row][cw + l15]      = (__bf16)gelu_fast(v0);
                hA[row][cw + 16 + l15] = (__bf16)gelu_fast(v1);
            }
        }
        BAR_LG();

        // ---- layer 2: K=256 from hA ----
        #pragma unroll
        for (int m = 0; m < 4; ++m) {
            f32x4 acc0 = {0.f, 0.f, 0.f, 0.f}, acc1 = {0.f, 0.f, 0.f, 0.f};
            __builtin_amdgcn_s_setprio(1);
            #pragma unroll
            for (int kc = 0; kc < 8; ++kc) {
                const bf16x8 a = *reinterpret_cast<const bf16x8*>(
                    &hA[m * 16 + l15][kc * 32 + lhi * 8]);
                acc0 = __builtin_amdgcn_mfma_f32_16x16x32_bf16(a, w2r[0][kc], acc0, 0, 0, 0);
                acc1 = __builtin_amdgcn_mfma_f32_16x16x32_bf16(a, w2r[1][kc], acc1, 0, 0, 0);
            }
            __builtin_amdgcn_s_setprio(0);
            #pragma unroll
            for (int r = 0; r < 4; ++r) {
                int row = m * 16 + lhi * 4 + r;
                hB[row][cw + l15]      = (__bf16)gelu_fast(acc0[r] + bb2[0]);
                hB[row][cw + 16 + l15] = (__bf16)gelu_fast(acc1[r] + bb2[1]);
            }
        }
        BAR_LG();

        // ---- layer 3: waves 0..3, 16 rows each ----
        if (wave < 4) {
            f32x4 a3 = {0.f, 0.f, 0.f, 0.f};
            __builtin_amdgcn_s_setprio(1);
            #pragma unroll
            for (int kc = 0; kc < 8; ++kc) {
                const bf16x8 a = *reinterpret_cast<const bf16x8*>(
                    &hB[wave * 16 + l15][kc * 32 + lhi * 8]);
                a3 = __builtin_amdgcn_mfma_f32_16x16x32_bf16(a, w3r[kc], a3, 0, 0, 0);
            }
            __builtin_amdgcn_s_setprio(0);
            if (l15 < OUT_DIM) {
                #pragma unroll
                for (int r = 0; r < 4; ++r) {
                    int row = T * M_TILE + wave * 16 + lhi * 4 + r;
                    if (row < N_Q) out[row * OUT_DIM + l15] = a3[r] + bb3;
                }
            }
        }
        cur ^= 1;
    }
}

// =============== fp32 exact path, shared by fixup + fallback ===============
// Keeps libm tanhf: wrap queries get the full-precision treatment.
__device__ __forceinline__ void mlp_row_fp32(
    int q, int gb, float dl, float dt, int t,
    const float* __restrict__ features,
    const float* __restrict__ W1, const float* __restrict__ b1,
    const float* __restrict__ W2, const float* __restrict__ b2,
    const float* __restrict__ W3, const float* __restrict__ b3,
    float* __restrict__ out, float* xs, float* h1s, float* h2s)
{
    if (t < 194)
        xs[t] = (t < 192) ? features[(size_t)t * FSTRIDE + gb]
                          : (t == 192 ? dl : dt);
    __syncthreads();
    {   // layer 1: col = t, 16-way batched loads
        float acc = b1[t];
        int k = 0;
        for (; k + 16 <= 194; k += 16) {
            float w[16];
            #pragma unroll
            for (int u = 0; u < 16; ++u) w[u] = W1[(k + u) * 256 + t];
            #pragma unroll
            for (int u = 0; u < 16; ++u) acc = fmaf(xs[k + u], w[u], acc);
        }
        for (; k < 194; ++k) acc = fmaf(xs[k], W1[k * 256 + t], acc);
        h1s[t] = gelu_tanh(acc);
    }
    __syncthreads();
    {   // layer 2
        float acc = b2[t];
        for (int k = 0; k < 256; k += 16) {
            float w[16];
            #pragma unroll
            for (int u = 0; u < 16; ++u) w[u] = W2[(k + u) * 256 + t];
            #pragma unroll
            for (int u = 0; u < 16; ++u) acc = fmaf(h1s[k + u], w[u], acc);
        }
        h2s[t] = gelu_tanh(acc);
    }
    __syncthreads();
    if (t < 64) {   // layer 3: 8 lanes/output x 8 outputs, shfl-reduce
        int j = t & 7, ch = t >> 3;
        float a3 = 0.0f;
        for (int k = ch * 32; k < ch * 32 + 32; ++k)
            a3 = fmaf(h2s[k], W3[k * 8 + j], a3);
        #pragma unroll
        for (int off = 8; off < 64; off <<= 1) a3 += __shfl_down(a3, off);
        if (t < 8) out[q * 8 + t] = a3 + b3[t];
    }
    __syncthreads();
}

// fp32 fixup, scan-driven: each block owns one 256-query chunk, finds wrap
// queries (|dlon| > 1) from gdl directly — no global atomics, no memset.
// Runs stream-ordered AFTER fused_mlp, so its fp32 overwrite is safe.
__global__ __launch_bounds__(256) void fixup_scan(
    const float* __restrict__ features,
    const float* __restrict__ W1, const float* __restrict__ b1,
    const float* __restrict__ W2, const float* __restrict__ b2,
    const float* __restrict__ W3, const float* __restrict__ b3,
    const int* __restrict__ gidx, const float* __restrict__ gdl,
    const float* __restrict__ gdt, float* __restrict__ out)
{
    const int t    = threadIdx.x;
    const int base = blockIdx.x * 256;

    __shared__ int lcnt;
    __shared__ int lst[256];
    if (t == 0) lcnt = 0;
    __syncthreads();
    {
        int q = base + t;
        if (q < N_Q && fabsf(gdl[q]) > 1.0f) {
            int s = atomicAdd(&lcnt, 1);     // LDS atomic, block-local
            lst[s] = q;
        }
    }
    __syncthreads();
    const int n = lcnt;
    if (n == 0) return;

    __shared__ float xs[194];
    __shared__ float h1s[HIDD];
    __shared__ float h2s[HIDD];

    for (int e = 0; e < n; ++e) {
        const int q = lst[e];
        mlp_row_fp32(q, gidx[q], gdl[q], gdt[q], t,
                     features, W1, b1, W2, b2, W3, b3, out, xs, h1s, h2s);
    }
}

// Fallback full-fp32 path (only if workspace too small — never in practice).
__global__ __launch_bounds__(256) void mlp_slow(
    const float* __restrict__ features, const float* __restrict__ lon_q,
    const float* __restrict__ lat_q, const float* __restrict__ lon_grid,
    const float* __restrict__ lat_grid,
    const float* __restrict__ W1, const float* __restrict__ b1,
    const float* __restrict__ W2, const float* __restrict__ b2,
    const float* __restrict__ W3, const float* __restrict__ b3,
    float* __restrict__ out)
{
    const int q = blockIdx.x;
    if (q >= N_Q) return;
    const int t = threadIdx.x;
    __shared__ float xs[194];
    __shared__ float h1s[HIDD];
    __shared__ float h2s[HIDD];
    int li, la; float dl, dt;
    nearest_lon(lon_grid, lon_q[q], &li, &dl);
    nearest_lat(lat_grid, lat_q[q], &la, &dt);
    mlp_row_fp32(q, li * N_LAT + la, dl, dt, t,
                 features, W1, b1, W2, b2, W3, b3, out, xs, h1s, h2s);
}

extern "C" void kernel_launch(void* const* d_in, const int* in_sizes, int n_in,
                              void* d_out, int out_size, void* d_ws, size_t ws_size,
                              hipStream_t stream)
{
    const float* features = (const float*)d_in[0];
    const float* lon_q    = (const float*)d_in[1];
    const float* lat_q    = (const float*)d_in[2];
    const float* lon_grid = (const float*)d_in[3];
    const float* lat_grid = (const float*)d_in[4];
    const float* W1       = (const float*)d_in[5];
    const float* b1       = (const float*)d_in[6];
    const float* W2       = (const float*)d_in[7];
    const float* b2       = (const float*)d_in[8];
    const float* W3       = (const float*)d_in[9];
    const float* b3       = (const float*)d_in[10];
    __bf16* ws = (__bf16*)d_ws;
    float* out = (float*)d_out;

    const size_t W_BYTES   = 135168ull * 2;                       // 270336
    const size_t FT_BYTES  = (size_t)N_CELLS * N_FEATC * 2;       // 99,532,800
    const size_t IDX_OFF   = W_BYTES + FT_BYTES;                  // 99,803,136
    const size_t PRE_BYTES = (size_t)N_Q * 12 + 64;
    const int use_ft  = (ws_size >= IDX_OFF) ? 1 : 0;
    const int use_pre = (ws_size >= IDX_OFF + PRE_BYTES) ? 1 : 0;

    __bf16* ft   = ws + 135168;
    char*  base  = (char*)d_ws;
    int*   gidx  = (int*)(base + IDX_OFF);
    float* gdl   = (float*)(base + IDX_OFF + (size_t)N_Q * 4);
    float* gdt   = (float*)(base + IDX_OFF + (size_t)N_Q * 8);

    prep<<<PREP_BLOCKS, 256, 0, stream>>>(
        features, lon_q, lat_q, lon_grid, lat_grid, W1, W2, W3,
        ws, ft, gidx, gdl, gdt, use_ft, use_pre);

    if (use_ft && use_pre) {
        fused_mlp<<<GRID_P, 512, 0, stream>>>(
            ws, ft, gidx, gdl, gdt, W1, b1, b2, b3, out);
        fixup_scan<<<(N_Q + 255) / 256, 256, 0, stream>>>(
            features, W1, b1, W2, b2, W3, b3, gidx, gdl, gdt, out);
    } else {
        mlp_slow<<<N_Q, 256, 0, stream>>>(
            features, lon_q, lat_q, lon_grid, lat_grid,
            W1, b1, W2, b2, W3, b3, out);
    }
}